// Round 7
// baseline (443.499 us; speedup 1.0000x reference)
//
#include <hip/hip_runtime.h>
#include <hip/hip_bf16.h>
#include <stdint.h>

typedef __attribute__((ext_vector_type(8))) short short8;
typedef __attribute__((ext_vector_type(4))) float f32x4;
typedef __attribute__((ext_vector_type(16))) float f32x16;

#define SEQ 2048
#define DMODEL 1024
#define NH 16
#define DKH 64

__device__ __forceinline__ uint16_t f2b(float f) {
  uint32_t u = __float_as_uint(f);
  uint32_t r = (u + 0x7fff + ((u >> 16) & 1)) >> 16;
  return (uint16_t)r;
}

__device__ __forceinline__ void gload16(const uint16_t* g, uint16_t* l) {
  __builtin_amdgcn_global_load_lds((const __attribute__((address_space(1))) void*)g,
                                   (__attribute__((address_space(3))) void*)l, 16, 0, 0);
}

// ---------------- cast x (f32 -> bf16), 4 elems/thread ----------------
__global__ __launch_bounds__(256) void k_castx(const float* __restrict__ x,
                                               uint16_t* __restrict__ xb) {
  int i = blockIdx.x * 256 + threadIdx.x;
  float4 v = reinterpret_cast<const float4*>(x)[i];
  uint16_t o[4] = {f2b(v.x), f2b(v.y), f2b(v.z), f2b(v.w)};
  reinterpret_cast<uint2*>(xb)[i] = *reinterpret_cast<uint2*>(o);
}

// ---------------- cast+transpose weight: W[K][N] f32 -> Wt[N][K] bf16 ----------------
__global__ __launch_bounds__(256) void k_tcast(const float* __restrict__ W,
                                               uint16_t* __restrict__ Wt, int K, int N) {
  __shared__ float tile[32][33];
  int n0 = blockIdx.x * 32, k0 = blockIdx.y * 32;
  int tx = threadIdx.x & 31, ty = threadIdx.x >> 5;
#pragma unroll
  for (int i = 0; i < 32; i += 8)
    tile[ty + i][tx] = W[(size_t)(k0 + ty + i) * N + n0 + tx];
  __syncthreads();
#pragma unroll
  for (int i = 0; i < 32; i += 8)
    Wt[(size_t)(n0 + ty + i) * K + k0 + tx] = f2b(tile[tx][ty + i]);
}

// ---------------- V transpose per (b,h): [2048][64] -> [64][2048] bf16 ----------------
__global__ __launch_bounds__(256) void k_vtrans(const uint16_t* __restrict__ V,
                                                uint16_t* __restrict__ Vt) {
  __shared__ uint16_t tile[64][72];
  const int s0 = blockIdx.x * 64;
  const uint16_t* Vp = V + (size_t)blockIdx.y * SEQ * DKH;
  uint16_t* Vtp = Vt + (size_t)blockIdx.y * SEQ * DKH;
  const int t = threadIdx.x;
#pragma unroll
  for (int i = t; i < 512; i += 256) {
    int r = i >> 3, c8 = (i & 7) << 3;
    *reinterpret_cast<uint4*>(&tile[r][c8]) =
        *reinterpret_cast<const uint4*>(Vp + (size_t)(s0 + r) * DKH + c8);
  }
  __syncthreads();
#pragma unroll
  for (int i = t; i < 512; i += 256) {
    int d = i >> 3, s8 = (i & 7) << 3;
    uint16_t tmp[8];
#pragma unroll
    for (int j = 0; j < 8; ++j) tmp[j] = tile[s8 + j][d];
    *reinterpret_cast<uint4*>(Vtp + (size_t)d * SEQ + s0 + s8) = *reinterpret_cast<uint4*>(tmp);
  }
}

// ---------------- GEMM v3: 256-row tile, BK=64, half-K-pipelined, counted vmcnt --------
// 8 phases per K-tile (quadrant x kk). Stage granularity = half-K (all rows x 32 cols):
// HK0(kt+1) issued during kk=0 phases, HK1(kt+1) during kk=1 phases. Waits: vmcnt(LHK)
// at mid-tile (HK1 of current tile ready) and boundary (HK0 of next ready) - never 0
// except the last tile. LDS layout [r/16][kk][16 rows][4 slots of 16B], slot swizzled by
// (r&3)^((r>>2)&1); global_load_lds dest stays linear (inverse-swizzled source).
#define MODE_QKV 0
#define MODE_RAW 1
#define MODE_RELU 2

template <int BN, int MODE>
__global__ __launch_bounds__(512, 2) void k_gemm2(
    const uint16_t* __restrict__ A, const uint16_t* __restrict__ Bt, int M, int N, int K,
    int nx, const float* __restrict__ bias0, const float* __restrict__ bias1,
    const float* __restrict__ bias2, uint16_t* __restrict__ ob0, uint16_t* __restrict__ ob1,
    uint16_t* __restrict__ ob2, float* __restrict__ of) {
  constexpr int ASZ = 256 * 64;  // u16 per A buffer
  constexpr int BSZ = BN * 64;
  __shared__ __align__(16) uint16_t lds[2 * (ASZ + BSZ)];
  uint16_t* const Abase = lds;
  uint16_t* const Bbase = lds + 2 * ASZ;
  constexpr int WN = (BN == 256) ? 4 : 2;    // waves along N
  constexpr int MREP = (BN == 256) ? 8 : 4;  // 16-row frags per wave
  constexpr int NQ = (BN == 256) ? 4 : 2;    // quadrant phases per kk
  constexpr int LHK = (BN == 256) ? 4 : 3;   // loads/thread per half-K unit (A+B)
  // XCD-chunked bijective remap (gridDim.x % 8 == 0)
  const int o = blockIdx.x;
  const int chunk = gridDim.x >> 3;
  const int wg = (o & 7) * chunk + (o >> 3);
  const int brow = (wg / nx) << 8;
  const int bcol = (wg % nx) * BN;
  const int t = threadIdx.x;
  const int wid = t >> 6, l = t & 63, g = l >> 4, lr = l & 15;
  const int wr = wid / WN, wc = wid % WN;
  const int wrow = wr * (MREP * 16);
  const int wcol = wc * 64;

  // staging: wave wid covers 16-row group wid (and wid+8 for the 2nd load); lane l ->
  // row = u*16 + (l>>2), source col slot gg (inverse swizzle), LDS dest linear l*16B.
  const int srow = (wid << 4) + (l >> 2);
  const int gg = (l & 3) ^ ((l >> 2) & 3) ^ ((l >> 4) & 1);
  const int ldso = (wid << 10) + l * 8;  // u16: group slab + lane slot

  auto stageA = [&](uint16_t* dst, int kcol, int kk) {
    gload16(A + (size_t)(brow + srow) * K + kcol + gg * 8, dst + ldso + kk * 512);
    gload16(A + (size_t)(brow + 128 + srow) * K + kcol + gg * 8, dst + 8192 + ldso + kk * 512);
  };
  auto stageB = [&](uint16_t* dst, int kcol, int kk) {
    gload16(Bt + (size_t)(bcol + srow) * K + kcol + gg * 8, dst + ldso + kk * 512);
    if (BN == 256)
      gload16(Bt + (size_t)(bcol + 128 + srow) * K + kcol + gg * 8, dst + 8192 + ldso + kk * 512);
  };

  const int sA = g ^ (lr & 3) ^ ((lr >> 2) & 1);  // lane-constant read slot
  auto rdfrag = [&](const uint16_t* buf, int r16, int kk) -> short8 {
    return *reinterpret_cast<const short8*>(buf + (r16 << 10) + kk * 512 + (lr << 5) + sA * 8);
  };

  f32x4 acc[MREP][4] = {};
  const int nt = K >> 6;

  // prologue: K-tile 0, both half-Ks; wait for HK0 only (HK1 stays in flight)
  stageA(Abase, 0, 0);
  stageB(Bbase, 0, 0);
  stageA(Abase, 32, 1);
  stageB(Bbase, 32, 1);
  asm volatile("s_waitcnt vmcnt(%0)" ::"i"(LHK) : "memory");
  __builtin_amdgcn_s_barrier();

  for (int kt = 0; kt < nt; ++kt) {
    const int cur = kt & 1;
    const uint16_t* Ac = Abase + cur * ASZ;
    const uint16_t* Bc = Bbase + cur * BSZ;
    uint16_t* An = Abase + (cur ^ 1) * ASZ;
    uint16_t* Bn = Bbase + (cur ^ 1) * BSZ;
    const bool pf = (kt + 1 < nt);
    const int knx = (kt + 1) << 6;
#pragma unroll
    for (int kk = 0; kk < 2; ++kk) {
#pragma unroll
      for (int q = 0; q < NQ; ++q) {
        const int mq = (BN == 256) ? (q >> 1) : 0;
        const int nq = (BN == 256) ? (q & 1) : q;
        short8 af[4], bf[2];
#pragma unroll
        for (int j = 0; j < 4; ++j) af[j] = rdfrag(Ac, (wrow >> 4) + mq * 4 + j, kk);
#pragma unroll
        for (int j = 0; j < 2; ++j) bf[j] = rdfrag(Bc, (wcol >> 4) + nq * 2 + j, kk);
        if (pf && q == 0) stageA(An, knx + kk * 32, kk);
        if (pf && q == 1) stageB(Bn, knx + kk * 32, kk);
        __builtin_amdgcn_s_setprio(1);
#pragma unroll
        for (int j = 0; j < 4; ++j)
#pragma unroll
          for (int j2 = 0; j2 < 2; ++j2)
            acc[mq * 4 + j][nq * 2 + j2] = __builtin_amdgcn_mfma_f32_16x16x32_bf16(
                af[j], bf[j2], acc[mq * 4 + j][nq * 2 + j2], 0, 0, 0);
        __builtin_amdgcn_s_setprio(0);
        if (q == NQ - 1) {
          if (kk == 0) {
            // mid-tile: HK1(kt) must be ready; outstanding = HK1(kt) + [HK0(kt+1) if pf]
            if (pf)
              asm volatile("s_waitcnt vmcnt(%0)" ::"i"(LHK) : "memory");
            else
              asm volatile("s_waitcnt vmcnt(0)" ::: "memory");
          } else if (pf) {
            // boundary: HK0(kt+1) ready; outstanding = HK0(kt+1) + HK1(kt+1)
            asm volatile("s_waitcnt vmcnt(%0)" ::"i"(LHK) : "memory");
          }
          __builtin_amdgcn_sched_barrier(0);
        }
        __builtin_amdgcn_s_barrier();
      }
    }
  }

  // epilogue
#pragma unroll
  for (int m = 0; m < MREP; ++m) {
#pragma unroll
    for (int n = 0; n < 4; ++n) {
#pragma unroll
      for (int qi = 0; qi < 4; ++qi) {
        int r = brow + wrow + m * 16 + g * 4 + qi;
        int c = bcol + wcol + n * 16 + lr;
        float v = acc[m][n][qi];
        if (MODE == MODE_QKV) {
          int which = c >> 10;  // uniform per block (bcol multiple of 256)
          int hd = c & 1023;
          const float* bp = which == 0 ? bias0 : (which == 1 ? bias1 : bias2);
          v += bp[hd];
          if (which == 0) v *= 0.1803368801f;  // 1/sqrt(dk) * log2(e)
          uint16_t* dst = which == 0 ? ob0 : (which == 1 ? ob1 : ob2);
          int b = r >> 11, tt = r & 2047;
          int h = hd >> 6, d = hd & 63;
          dst[((size_t)((b * NH + h) * SEQ + tt)) * DKH + d] = f2b(v);
        } else if (MODE == MODE_RELU) {
          v += bias0[c];
          v = fmaxf(v, 0.0f);
          ob0[(size_t)r * N + c] = f2b(v);
        } else {  // MODE_RAW
          of[(size_t)r * N + c] = v;
        }
      }
    }
  }
}

// ---------------- attention v5: XCD-local bh grouping (1D grid 1024) -------------------
__global__ __launch_bounds__(256) void k_attn(const uint16_t* __restrict__ Qb,
                                              const uint16_t* __restrict__ Kb,
                                              const uint16_t* __restrict__ Vtg,
                                              uint16_t* __restrict__ ctx) {
  __shared__ __align__(16) uint16_t Ks[2][64 * 64];
  __shared__ __align__(16) uint16_t Vs[2][64 * 64];
  __shared__ float l_arr[4][32];
  const int o = blockIdx.x;
  const int wg = (o & 7) * 128 + (o >> 3);
  const int qt = wg & 15;
  const int bh = wg >> 4;
  const int b = bh >> 4, h = bh & 15;
  const uint16_t* Qp = Qb + (size_t)bh * SEQ * DKH;
  const uint16_t* Kp = Kb + (size_t)bh * SEQ * DKH;
  const uint16_t* Vp = Vtg + (size_t)bh * SEQ * DKH;  // [64][2048]
  const int t = threadIdx.x, w = t >> 6, l = t & 63;
  const int lo5 = l & 31, hh = l >> 5;
  const int qbase = qt * 128 + w * 32;

  short8 qf[4];
#pragma unroll
  for (int kc = 0; kc < 4; ++kc)
    qf[kc] = *reinterpret_cast<const short8*>(Qp + (size_t)(qbase + lo5) * DKH + kc * 16 + hh * 8);

  f32x16 oacc[2] = {};
  float lsum = 0.f;

  const int swz = ((l & 7) ^ ((l >> 3) & 7)) << 3;
  const int ci0 = w * 2, ci1 = w * 2 + 1;
  const int r0 = ci0 * 8 + (l >> 3), r1 = ci1 * 8 + (l >> 3);
  uint16_t* ldsK0 = &Ks[0][0] + ci0 * 512 + l * 8;
  uint16_t* ldsK1 = &Ks[0][0] + ci1 * 512 + l * 8;
  uint16_t* ldsV0 = &Vs[0][0] + ci0 * 512 + l * 8;
  uint16_t* ldsV1 = &Vs[0][0] + ci1 * 512 + l * 8;
  const uint16_t* gK0 = Kp + (size_t)r0 * DKH + swz;
  const uint16_t* gK1 = Kp + (size_t)r1 * DKH + swz;
  const uint16_t* gV0 = Vp + (size_t)r0 * SEQ + swz;
  const uint16_t* gV1 = Vp + (size_t)r1 * SEQ + swz;

  gload16(gK0, ldsK0);
  gload16(gK1, ldsK1);
  gload16(gV0, ldsV0);
  gload16(gV1, ldsV1);
  __syncthreads();

  for (int tile = 0; tile < 32; ++tile) {
    const int cur = tile & 1;
    if (tile < 31) {
      const int nxt = (cur ^ 1) * 4096;
      const size_t s0n = (size_t)(tile + 1) * 64;
      gload16(gK0 + s0n * DKH, ldsK0 + nxt);
      gload16(gK1 + s0n * DKH, ldsK1 + nxt);
      gload16(gV0 + s0n, ldsV0 + nxt);
      gload16(gV1 + s0n, ldsV1 + nxt);
    }
    const char* Kbuf = reinterpret_cast<const char*>(&Ks[cur][0]);
    const char* Vbuf = reinterpret_cast<const char*>(&Vs[cur][0]);

#pragma unroll
    for (int sblk = 0; sblk < 2; ++sblk) {
      short8 kf[4];
      const int krow = sblk * 32 + lo5;
      const int kxor = (krow & 7) << 4;
#pragma unroll
      for (int kc = 0; kc < 4; ++kc) {
        int cb = (kc * 32 + hh * 16) ^ kxor;
        kf[kc] = *reinterpret_cast<const short8*>(Kbuf + krow * 128 + cb);
      }
      short8 vf[2][2];
#pragma unroll
      for (int scl = 0; scl < 2; ++scl)
#pragma unroll
        for (int dblk = 0; dblk < 2; ++dblk) {
          int vrow = dblk * 32 + lo5;
          int cb = (sblk * 64 + scl * 32 + hh * 16) ^ ((vrow & 7) << 4);
          vf[scl][dblk] = *reinterpret_cast<const short8*>(Vbuf + vrow * 128 + cb);
        }

      f32x16 sa = {};
      __builtin_amdgcn_s_setprio(1);
#pragma unroll
      for (int kc = 0; kc < 4; ++kc)
        sa = __builtin_amdgcn_mfma_f32_32x32x16_bf16(kf[kc], qf[kc], sa, 0, 0, 0);
      __builtin_amdgcn_s_setprio(0);

      float p[16];
      float ls = 0.f;
#pragma unroll
      for (int r = 0; r < 16; ++r) {
        p[r] = __builtin_amdgcn_exp2f(sa[r]);
        ls += p[r];
      }
      lsum += ls;

      uint32_t clo[4], chi[4];
#pragma unroll
      for (int m = 0; m < 4; ++m) {
        asm("v_cvt_pk_bf16_f32 %0, %1, %2" : "=v"(clo[m]) : "v"(p[4 * m]), "v"(p[4 * m + 1]));
        asm("v_cvt_pk_bf16_f32 %0, %1, %2" : "=v"(chi[m]) : "v"(p[4 * m + 2]), "v"(p[4 * m + 3]));
      }

#pragma unroll
      for (int scl = 0; scl < 2; ++scl) {
        uint32_t a0 = clo[2 * scl], b0 = clo[2 * scl + 1];
        uint32_t a1 = chi[2 * scl], b1 = chi[2 * scl + 1];
        asm("v_permlane32_swap_b32 %0, %1" : "+v"(a0), "+v"(b0));
        asm("v_permlane32_swap_b32 %0, %1" : "+v"(a1), "+v"(b1));
        union {
          uint32_t u[4];
          short8 s;
        } pu;
        pu.u[0] = a0;
        pu.u[1] = a1;
        pu.u[2] = b0;
        pu.u[3] = b1;
        __builtin_amdgcn_s_setprio(1);
#pragma unroll
        for (int dblk = 0; dblk < 2; ++dblk)
          oacc[dblk] = __builtin_amdgcn_mfma_f32_32x32x16_bf16(pu.s, vf[scl][dblk], oacc[dblk], 0, 0, 0);
        __builtin_amdgcn_s_setprio(0);
      }
    }
    __syncthreads();
  }

  {
    float full = lsum + __shfl_xor(lsum, 32, 64);
    if (l < 32) l_arr[w][lo5] = full;
  }
#pragma unroll
  for (int r = 0; r < 16; ++r) {
    int q = (r & 3) + 8 * (r >> 2) + 4 * hh;
    float li = 1.0f / l_arr[w][q];
    int rowg = b * SEQ + qbase + q;
#pragma unroll
    for (int dblk = 0; dblk < 2; ++dblk) {
      int colg = h * DKH + dblk * 32 + lo5;
      ctx[(size_t)rowg * DMODEL + colg] = f2b(oacc[dblk][r] * li);
    }
  }
}

// ---------------- LayerNorm over (in + bias + res) ----------------
template <bool WRITE_B>
__global__ __launch_bounds__(256) void k_ln(const float* __restrict__ in,
                                            const float* __restrict__ bias,
                                            const float* __restrict__ res,
                                            const float* __restrict__ gam,
                                            const float* __restrict__ bet,
                                            float* __restrict__ outf,
                                            uint16_t* __restrict__ outb) {
  const int row = blockIdx.x;
  const int t = threadIdx.x, lane = t & 63, w = t >> 6;
  float4 v = reinterpret_cast<const float4*>(in + (size_t)row * DMODEL)[t];
  float4 bb0 = reinterpret_cast<const float4*>(bias)[t];
  float4 rr = reinterpret_cast<const float4*>(res + (size_t)row * DMODEL)[t];
  v.x += bb0.x + rr.x;
  v.y += bb0.y + rr.y;
  v.z += bb0.z + rr.z;
  v.w += bb0.w + rr.w;
  float s = v.x + v.y + v.z + v.w;
  float s2 = v.x * v.x + v.y * v.y + v.z * v.z + v.w * v.w;
#pragma unroll
  for (int off = 1; off < 64; off <<= 1) {
    s += __shfl_xor(s, off, 64);
    s2 += __shfl_xor(s2, off, 64);
  }
  __shared__ float rs[4], rq[4];
  if (lane == 0) {
    rs[w] = s;
    rq[w] = s2;
  }
  __syncthreads();
  float ts = rs[0] + rs[1] + rs[2] + rs[3];
  float tq = rq[0] + rq[1] + rq[2] + rq[3];
  const float inv = 1.0f / DMODEL;
  float mu = ts * inv;
  float var = tq * inv - mu * mu;
  float rstd = rsqrtf(var + 1e-5f);
  float4 gg = reinterpret_cast<const float4*>(gam)[t];
  float4 bb = reinterpret_cast<const float4*>(bet)[t];
  float4 y;
  y.x = (v.x - mu) * rstd * gg.x + bb.x;
  y.y = (v.y - mu) * rstd * gg.y + bb.y;
  y.z = (v.z - mu) * rstd * gg.z + bb.z;
  y.w = (v.w - mu) * rstd * gg.w + bb.w;
  reinterpret_cast<float4*>(outf)[(size_t)row * 256 + t] = y;
  if (WRITE_B) {
    uint16_t o[4] = {f2b(y.x), f2b(y.y), f2b(y.z), f2b(y.w)};
    reinterpret_cast<uint2*>(outb)[(size_t)row * 256 + t] = *reinterpret_cast<uint2*>(o);
  }
}

extern "C" void kernel_launch(void* const* d_in, const int* in_sizes, int n_in, void* d_out,
                              int out_size, void* d_ws, size_t ws_size, hipStream_t stream) {
  const float* x = (const float*)d_in[0];
  const float* Wq = (const float*)d_in[1];
  const float* bq = (const float*)d_in[2];
  const float* Wk = (const float*)d_in[3];
  const float* bk = (const float*)d_in[4];
  const float* Wv = (const float*)d_in[5];
  const float* bv = (const float*)d_in[6];
  const float* Wo = (const float*)d_in[7];
  const float* bo = (const float*)d_in[8];
  const float* g1 = (const float*)d_in[9];
  const float* be1 = (const float*)d_in[10];
  const float* W1 = (const float*)d_in[11];
  const float* b1 = (const float*)d_in[12];
  const float* W2 = (const float*)d_in[13];
  const float* b2 = (const float*)d_in[14];
  const float* g2 = (const float*)d_in[15];
  const float* be2 = (const float*)d_in[16];

  char* ws = (char*)d_ws;
  size_t off = 0;
  auto alloc = [&](size_t bytes) {
    char* p = ws + off;
    off += (bytes + 255) & ~(size_t)255;
    return p;
  };
  uint16_t* wt_qkv = (uint16_t*)alloc(3072ull * 1024 * 2);
  uint16_t* wt_o = (uint16_t*)alloc(1024ull * 1024 * 2);
  uint16_t* wt_1 = (uint16_t*)alloc(4096ull * 1024 * 2);
  uint16_t* wt_2 = (uint16_t*)alloc(1024ull * 4096 * 2);
  uint16_t* xb = (uint16_t*)alloc(8192ull * 1024 * 2);  // x bf16; later aliased as ctx
  float* sum1 = (float*)alloc(8192ull * 1024 * 4);      // raw GEMM f32 out (Wo, then FFN2)
  float* x1f = (float*)alloc(8192ull * 1024 * 4);       // LN1 out f32; vt aliases (dead before LN1)
  char* big = alloc(16777216ull + 67108864ull);         // QKV (48MB) -> x1b(16MB)+h(64MB)
  uint16_t* Qbuf = (uint16_t*)big;
  uint16_t* Kbuf = (uint16_t*)(big + 16777216ull);
  uint16_t* Vbuf = (uint16_t*)(big + 2 * 16777216ull);
  uint16_t* vt = (uint16_t*)x1f;
  uint16_t* ctx = xb;
  uint16_t* x1b = (uint16_t*)big;
  uint16_t* hbuf = (uint16_t*)(big + 16777216ull);
  (void)ws_size;

  // 1. weight prep
  k_tcast<<<dim3(32, 32), 256, 0, stream>>>(Wq, wt_qkv, 1024, 1024);
  k_tcast<<<dim3(32, 32), 256, 0, stream>>>(Wk, wt_qkv + 1024 * 1024, 1024, 1024);
  k_tcast<<<dim3(32, 32), 256, 0, stream>>>(Wv, wt_qkv + 2 * 1024 * 1024, 1024, 1024);
  k_tcast<<<dim3(32, 32), 256, 0, stream>>>(Wo, wt_o, 1024, 1024);
  k_tcast<<<dim3(128, 32), 256, 0, stream>>>(W1, wt_1, 1024, 4096);
  k_tcast<<<dim3(32, 128), 256, 0, stream>>>(W2, wt_2, 4096, 1024);
  // 2. cast x
  k_castx<<<8192, 256, 0, stream>>>(x, xb);
  // 3. QKV projection (Q pre-scaled by 0.125*log2e for exp2 softmax)
  k_gemm2<256, MODE_QKV><<<384, 512, 0, stream>>>(
      xb, wt_qkv, 8192, 3072, 1024, 12, bq, bk, bv, Qbuf, Kbuf, Vbuf, nullptr);
  // 3.5 V transpose
  k_vtrans<<<dim3(32, 64), 256, 0, stream>>>(Vbuf, vt);
  // 4. attention -> ctx (XCD-local bh grouping)
  k_attn<<<1024, 256, 0, stream>>>(Qbuf, Kbuf, vt, ctx);
  // 5. Wo projection raw -> sum1 (bias+residual folded into LN1)
  k_gemm2<128, MODE_RAW><<<256, 512, 0, stream>>>(
      ctx, wt_o, 8192, 1024, 1024, 8, nullptr, nullptr, nullptr, nullptr, nullptr, nullptr, sum1);
  // 6. LN1(sum1 + bo + x) -> x1 (f32 + bf16)
  k_ln<true><<<8192, 256, 0, stream>>>(sum1, bo, x, g1, be1, x1f, x1b);
  // 7. FFN1: relu(x1 @ W1 + b1) -> h bf16
  k_gemm2<256, MODE_RELU><<<512, 512, 0, stream>>>(
      x1b, wt_1, 8192, 4096, 1024, 16, b1, nullptr, nullptr, hbuf, nullptr, nullptr, nullptr);
  // 8. FFN2 raw -> sum1
  k_gemm2<128, MODE_RAW><<<256, 512, 0, stream>>>(
      hbuf, wt_2, 8192, 1024, 4096, 8, nullptr, nullptr, nullptr, nullptr, nullptr, nullptr, sum1);
  // 9. LN2(sum1 + b2 + x1f) -> output (f32)
  k_ln<false><<<8192, 256, 0, stream>>>(sum1, b2, x1f, g2, be2, (float*)d_out, nullptr);
}

// Round 8
// 418.397 us; speedup vs baseline: 1.0600x; 1.0600x over previous
//
#include <hip/hip_runtime.h>
#include <hip/hip_bf16.h>
#include <stdint.h>

typedef __attribute__((ext_vector_type(8))) short short8;
typedef __attribute__((ext_vector_type(4))) float f32x4;
typedef __attribute__((ext_vector_type(16))) float f32x16;

#define SEQ 2048
#define DMODEL 1024
#define NH 16
#define DKH 64

__device__ __forceinline__ uint16_t f2b(float f) {
  uint32_t u = __float_as_uint(f);
  uint32_t r = (u + 0x7fff + ((u >> 16) & 1)) >> 16;
  return (uint16_t)r;
}

__device__ __forceinline__ void gload16(const uint16_t* g, uint16_t* l) {
  __builtin_amdgcn_global_load_lds((const __attribute__((address_space(1))) void*)g,
                                   (__attribute__((address_space(3))) void*)l, 16, 0, 0);
}

// ---------------- cast x (f32 -> bf16), 4 elems/thread ----------------
__global__ __launch_bounds__(256) void k_castx(const float* __restrict__ x,
                                               uint16_t* __restrict__ xb) {
  int i = blockIdx.x * 256 + threadIdx.x;
  float4 v = reinterpret_cast<const float4*>(x)[i];
  uint16_t o[4] = {f2b(v.x), f2b(v.y), f2b(v.z), f2b(v.w)};
  reinterpret_cast<uint2*>(xb)[i] = *reinterpret_cast<uint2*>(o);
}

// ---------------- cast+transpose weight: W[K][N] f32 -> Wt[N][K] bf16 ----------------
__global__ __launch_bounds__(256) void k_tcast(const float* __restrict__ W,
                                               uint16_t* __restrict__ Wt, int K, int N) {
  __shared__ float tile[32][33];
  int n0 = blockIdx.x * 32, k0 = blockIdx.y * 32;
  int tx = threadIdx.x & 31, ty = threadIdx.x >> 5;
#pragma unroll
  for (int i = 0; i < 32; i += 8)
    tile[ty + i][tx] = W[(size_t)(k0 + ty + i) * N + n0 + tx];
  __syncthreads();
#pragma unroll
  for (int i = 0; i < 32; i += 8)
    Wt[(size_t)(n0 + ty + i) * K + k0 + tx] = f2b(tile[tx][ty + i]);
}

// ---------------- V transpose per (b,h): [2048][64] -> [64][2048] bf16 ----------------
__global__ __launch_bounds__(256) void k_vtrans(const uint16_t* __restrict__ V,
                                                uint16_t* __restrict__ Vt) {
  __shared__ uint16_t tile[64][72];
  const int s0 = blockIdx.x * 64;
  const uint16_t* Vp = V + (size_t)blockIdx.y * SEQ * DKH;
  uint16_t* Vtp = Vt + (size_t)blockIdx.y * SEQ * DKH;
  const int t = threadIdx.x;
#pragma unroll
  for (int i = t; i < 512; i += 256) {
    int r = i >> 3, c8 = (i & 7) << 3;
    *reinterpret_cast<uint4*>(&tile[r][c8]) =
        *reinterpret_cast<const uint4*>(Vp + (size_t)(s0 + r) * DKH + c8);
  }
  __syncthreads();
#pragma unroll
  for (int i = t; i < 512; i += 256) {
    int d = i >> 3, s8 = (i & 7) << 3;
    uint16_t tmp[8];
#pragma unroll
    for (int j = 0; j < 8; ++j) tmp[j] = tile[s8 + j][d];
    *reinterpret_cast<uint4*>(Vtp + (size_t)d * SEQ + s0 + s8) = *reinterpret_cast<uint4*>(tmp);
  }
}

// ---------------- GEMM v2 (R6 schedule): 256-row tile, BK=64, 8 waves ------------------
// 1D grid, XCD-chunked bijective swizzle (nwg % 8 == 0).
#define MODE_QKV 0
#define MODE_RAW 1
#define MODE_RELU 2

template <int BN, int MODE>
__global__ __launch_bounds__(512, 2) void k_gemm2(
    const uint16_t* __restrict__ A, const uint16_t* __restrict__ Bt, int M, int N, int K,
    int nx, const float* __restrict__ bias0, const float* __restrict__ bias1,
    const float* __restrict__ bias2, uint16_t* __restrict__ ob0, uint16_t* __restrict__ ob1,
    uint16_t* __restrict__ ob2, float* __restrict__ of) {
  constexpr int ASZ = 256 * 64;  // u16 per A buffer
  constexpr int BSZ = BN * 64;
  __shared__ __align__(16) uint16_t lds[2 * (ASZ + BSZ)];
  uint16_t* const Abase = lds;
  uint16_t* const Bbase = lds + 2 * ASZ;
  constexpr int WN = (BN == 256) ? 4 : 2;   // waves along N
  constexpr int MREP = (BN == 256) ? 8 : 4; // 16-row frags per wave
  constexpr int NPH = (BN == 256) ? 4 : 2;  // phases per K-tile
  // XCD-chunked bijective remap
  const int o = blockIdx.x;
  const int chunk = gridDim.x >> 3;
  const int wg = (o & 7) * chunk + (o >> 3);
  const int brow = (wg / nx) << 8;
  const int bcol = (wg % nx) * BN;
  const int t = threadIdx.x;
  const int wid = t >> 6, l = t & 63, g = l >> 4, lr = l & 15;
  const int wr = wid / WN, wc = wid % WN;
  const int wrow = wr * (MREP * 16);
  const int wcol = wc * 64;

  const int srow = t >> 3;
  const int ss0 = (t & 7) ^ (srow & 7);
  const int ss1 = (t & 7) ^ ((srow + 64) & 7);

  auto stage_half = [&](const uint16_t* gsrc, int grow0, int kk, uint16_t* ldst) {
    gload16(gsrc + (size_t)(grow0 + srow) * K + kk + ss0 * 8, ldst + t * 8);
    gload16(gsrc + (size_t)(grow0 + srow + 64) * K + kk + ss1 * 8, ldst + 4096 + t * 8);
  };
  auto rdfrag = [&](const uint16_t* buf, int ar, int kk) -> short8 {
    int slot = ((kk << 2) + g) ^ (ar & 7);
    return *reinterpret_cast<const short8*>(buf + ar * 64 + slot * 8);
  };

  f32x4 acc[MREP][4] = {};
  const int nt = K >> 6;

  stage_half(A, brow, 0, Abase);
  stage_half(A, brow + 128, 0, Abase + 8192);
  stage_half(Bt, bcol, 0, Bbase);
  if (BN == 256) stage_half(Bt, bcol + 128, 0, Bbase + 8192);
  __syncthreads();

  for (int kt = 0; kt < nt; ++kt) {
    const int cur = kt & 1;
    const uint16_t* Ac = Abase + cur * ASZ;
    const uint16_t* Bc = Bbase + cur * BSZ;
    uint16_t* An = Abase + (cur ^ 1) * ASZ;
    uint16_t* Bn = Bbase + (cur ^ 1) * BSZ;
    const bool pf = (kt + 1 < nt);
    const int knx = (kt + 1) << 6;
#pragma unroll
    for (int q = 0; q < NPH; ++q) {
      const int mq = (BN == 256) ? (q >> 1) : 0;
      const int nq = (BN == 256) ? (q & 1) : q;
      short8 af[4][2], bf[2][2];
#pragma unroll
      for (int j = 0; j < 4; ++j)
#pragma unroll
        for (int kk = 0; kk < 2; ++kk)
          af[j][kk] = rdfrag(Ac, wrow + (mq * 4 + j) * 16 + lr, kk);
#pragma unroll
      for (int j = 0; j < 2; ++j)
#pragma unroll
        for (int kk = 0; kk < 2; ++kk)
          bf[j][kk] = rdfrag(Bc, wcol + (nq * 2 + j) * 16 + lr, kk);
      if (pf) {
        if (q == 0) {
          stage_half(A, brow, knx, An);
          stage_half(A, brow + 128, knx, An + 8192);
          if (BN == 128) stage_half(Bt, bcol, knx, Bn);
        }
        if (BN == 256 && q == 1) stage_half(Bt, bcol, knx, Bn);
        if (BN == 256 && q == 2) stage_half(Bt, bcol + 128, knx, Bn + 8192);
      }
      __builtin_amdgcn_s_barrier();
      __builtin_amdgcn_s_setprio(1);
#pragma unroll
      for (int j = 0; j < 4; ++j)
#pragma unroll
        for (int j2 = 0; j2 < 2; ++j2)
#pragma unroll
          for (int kk = 0; kk < 2; ++kk)
            acc[mq * 4 + j][nq * 2 + j2] = __builtin_amdgcn_mfma_f32_16x16x32_bf16(
                af[j][kk], bf[j2][kk], acc[mq * 4 + j][nq * 2 + j2], 0, 0, 0);
      __builtin_amdgcn_s_setprio(0);
      if (q == NPH - 1) {
        asm volatile("s_waitcnt vmcnt(0)" ::: "memory");
        __builtin_amdgcn_s_barrier();
        __builtin_amdgcn_sched_barrier(0);
      } else {
        __builtin_amdgcn_s_barrier();
      }
    }
  }

  // epilogue
#pragma unroll
  for (int m = 0; m < MREP; ++m) {
#pragma unroll
    for (int n = 0; n < 4; ++n) {
#pragma unroll
      for (int qi = 0; qi < 4; ++qi) {
        int r = brow + wrow + m * 16 + g * 4 + qi;
        int c = bcol + wcol + n * 16 + lr;
        float v = acc[m][n][qi];
        if (MODE == MODE_QKV) {
          int which = c >> 10;  // uniform per block (bcol multiple of 128, 1024%128==0)
          int hd = c & 1023;
          const float* bp = which == 0 ? bias0 : (which == 1 ? bias1 : bias2);
          v += bp[hd];
          if (which == 0) v *= 0.1803368801f;  // 1/sqrt(dk) * log2(e)
          uint16_t* dst = which == 0 ? ob0 : (which == 1 ? ob1 : ob2);
          int b = r >> 11, tt = r & 2047;
          int h = hd >> 6, d = hd & 63;
          dst[((size_t)((b * NH + h) * SEQ + tt)) * DKH + d] = f2b(v);
        } else if (MODE == MODE_RELU) {
          v += bias0[c];
          v = fmaxf(v, 0.0f);
          ob0[(size_t)r * N + c] = f2b(v);
        } else {  // MODE_RAW
          of[(size_t)r * N + c] = v;
        }
      }
    }
  }
}

// ---------------- attention v5: XCD-local bh grouping (1D grid 1024) -------------------
__global__ __launch_bounds__(256) void k_attn(const uint16_t* __restrict__ Qb,
                                              const uint16_t* __restrict__ Kb,
                                              const uint16_t* __restrict__ Vtg,
                                              uint16_t* __restrict__ ctx) {
  __shared__ __align__(16) uint16_t Ks[2][64 * 64];
  __shared__ __align__(16) uint16_t Vs[2][64 * 64];
  __shared__ float l_arr[4][32];
  const int o = blockIdx.x;
  const int wg = (o & 7) * 128 + (o >> 3);
  const int qt = wg & 15;
  const int bh = wg >> 4;
  const int b = bh >> 4, h = bh & 15;
  const uint16_t* Qp = Qb + (size_t)bh * SEQ * DKH;
  const uint16_t* Kp = Kb + (size_t)bh * SEQ * DKH;
  const uint16_t* Vp = Vtg + (size_t)bh * SEQ * DKH;  // [64][2048]
  const int t = threadIdx.x, w = t >> 6, l = t & 63;
  const int lo5 = l & 31, hh = l >> 5;
  const int qbase = qt * 128 + w * 32;

  short8 qf[4];
#pragma unroll
  for (int kc = 0; kc < 4; ++kc)
    qf[kc] = *reinterpret_cast<const short8*>(Qp + (size_t)(qbase + lo5) * DKH + kc * 16 + hh * 8);

  f32x16 oacc[2] = {};
  float lsum = 0.f;

  const int swz = ((l & 7) ^ ((l >> 3) & 7)) << 3;
  const int ci0 = w * 2, ci1 = w * 2 + 1;
  const int r0 = ci0 * 8 + (l >> 3), r1 = ci1 * 8 + (l >> 3);
  uint16_t* ldsK0 = &Ks[0][0] + ci0 * 512 + l * 8;
  uint16_t* ldsK1 = &Ks[0][0] + ci1 * 512 + l * 8;
  uint16_t* ldsV0 = &Vs[0][0] + ci0 * 512 + l * 8;
  uint16_t* ldsV1 = &Vs[0][0] + ci1 * 512 + l * 8;
  const uint16_t* gK0 = Kp + (size_t)r0 * DKH + swz;
  const uint16_t* gK1 = Kp + (size_t)r1 * DKH + swz;
  const uint16_t* gV0 = Vp + (size_t)r0 * SEQ + swz;
  const uint16_t* gV1 = Vp + (size_t)r1 * SEQ + swz;

  gload16(gK0, ldsK0);
  gload16(gK1, ldsK1);
  gload16(gV0, ldsV0);
  gload16(gV1, ldsV1);
  __syncthreads();

  for (int tile = 0; tile < 32; ++tile) {
    const int cur = tile & 1;
    if (tile < 31) {
      const int nxt = (cur ^ 1) * 4096;
      const size_t s0n = (size_t)(tile + 1) * 64;
      gload16(gK0 + s0n * DKH, ldsK0 + nxt);
      gload16(gK1 + s0n * DKH, ldsK1 + nxt);
      gload16(gV0 + s0n, ldsV0 + nxt);
      gload16(gV1 + s0n, ldsV1 + nxt);
    }
    const char* Kbuf = reinterpret_cast<const char*>(&Ks[cur][0]);
    const char* Vbuf = reinterpret_cast<const char*>(&Vs[cur][0]);

#pragma unroll
    for (int sblk = 0; sblk < 2; ++sblk) {
      short8 kf[4];
      const int krow = sblk * 32 + lo5;
      const int kxor = (krow & 7) << 4;
#pragma unroll
      for (int kc = 0; kc < 4; ++kc) {
        int cb = (kc * 32 + hh * 16) ^ kxor;
        kf[kc] = *reinterpret_cast<const short8*>(Kbuf + krow * 128 + cb);
      }
      short8 vf[2][2];
#pragma unroll
      for (int scl = 0; scl < 2; ++scl)
#pragma unroll
        for (int dblk = 0; dblk < 2; ++dblk) {
          int vrow = dblk * 32 + lo5;
          int cb = (sblk * 64 + scl * 32 + hh * 16) ^ ((vrow & 7) << 4);
          vf[scl][dblk] = *reinterpret_cast<const short8*>(Vbuf + vrow * 128 + cb);
        }

      f32x16 sa = {};
      __builtin_amdgcn_s_setprio(1);
#pragma unroll
      for (int kc = 0; kc < 4; ++kc)
        sa = __builtin_amdgcn_mfma_f32_32x32x16_bf16(kf[kc], qf[kc], sa, 0, 0, 0);
      __builtin_amdgcn_s_setprio(0);

      float p[16];
      float ls = 0.f;
#pragma unroll
      for (int r = 0; r < 16; ++r) {
        p[r] = __builtin_amdgcn_exp2f(sa[r]);
        ls += p[r];
      }
      lsum += ls;

      uint32_t clo[4], chi[4];
#pragma unroll
      for (int m = 0; m < 4; ++m) {
        asm("v_cvt_pk_bf16_f32 %0, %1, %2" : "=v"(clo[m]) : "v"(p[4 * m]), "v"(p[4 * m + 1]));
        asm("v_cvt_pk_bf16_f32 %0, %1, %2" : "=v"(chi[m]) : "v"(p[4 * m + 2]), "v"(p[4 * m + 3]));
      }

#pragma unroll
      for (int scl = 0; scl < 2; ++scl) {
        uint32_t a0 = clo[2 * scl], b0 = clo[2 * scl + 1];
        uint32_t a1 = chi[2 * scl], b1 = chi[2 * scl + 1];
        asm("v_permlane32_swap_b32 %0, %1" : "+v"(a0), "+v"(b0));
        asm("v_permlane32_swap_b32 %0, %1" : "+v"(a1), "+v"(b1));
        union {
          uint32_t u[4];
          short8 s;
        } pu;
        pu.u[0] = a0;
        pu.u[1] = a1;
        pu.u[2] = b0;
        pu.u[3] = b1;
        __builtin_amdgcn_s_setprio(1);
#pragma unroll
        for (int dblk = 0; dblk < 2; ++dblk)
          oacc[dblk] = __builtin_amdgcn_mfma_f32_32x32x16_bf16(pu.s, vf[scl][dblk], oacc[dblk], 0, 0, 0);
        __builtin_amdgcn_s_setprio(0);
      }
    }
    __syncthreads();
  }

  {
    float full = lsum + __shfl_xor(lsum, 32, 64);
    if (l < 32) l_arr[w][lo5] = full;
  }
#pragma unroll
  for (int r = 0; r < 16; ++r) {
    int q = (r & 3) + 8 * (r >> 2) + 4 * hh;
    float li = 1.0f / l_arr[w][q];
    int rowg = b * SEQ + qbase + q;
#pragma unroll
    for (int dblk = 0; dblk < 2; ++dblk) {
      int colg = h * DKH + dblk * 32 + lo5;
      ctx[(size_t)rowg * DMODEL + colg] = f2b(oacc[dblk][r] * li);
    }
  }
}

// ---------------- LayerNorm over (in + bias + res) ----------------
template <bool WRITE_B>
__global__ __launch_bounds__(256) void k_ln(const float* __restrict__ in,
                                            const float* __restrict__ bias,
                                            const float* __restrict__ res,
                                            const float* __restrict__ gam,
                                            const float* __restrict__ bet,
                                            float* __restrict__ outf,
                                            uint16_t* __restrict__ outb) {
  const int row = blockIdx.x;
  const int t = threadIdx.x, lane = t & 63, w = t >> 6;
  float4 v = reinterpret_cast<const float4*>(in + (size_t)row * DMODEL)[t];
  float4 bb0 = reinterpret_cast<const float4*>(bias)[t];
  float4 rr = reinterpret_cast<const float4*>(res + (size_t)row * DMODEL)[t];
  v.x += bb0.x + rr.x;
  v.y += bb0.y + rr.y;
  v.z += bb0.z + rr.z;
  v.w += bb0.w + rr.w;
  float s = v.x + v.y + v.z + v.w;
  float s2 = v.x * v.x + v.y * v.y + v.z * v.z + v.w * v.w;
#pragma unroll
  for (int off = 1; off < 64; off <<= 1) {
    s += __shfl_xor(s, off, 64);
    s2 += __shfl_xor(s2, off, 64);
  }
  __shared__ float rs[4], rq[4];
  if (lane == 0) {
    rs[w] = s;
    rq[w] = s2;
  }
  __syncthreads();
  float ts = rs[0] + rs[1] + rs[2] + rs[3];
  float tq = rq[0] + rq[1] + rq[2] + rq[3];
  const float inv = 1.0f / DMODEL;
  float mu = ts * inv;
  float var = tq * inv - mu * mu;
  float rstd = rsqrtf(var + 1e-5f);
  float4 gg = reinterpret_cast<const float4*>(gam)[t];
  float4 bb = reinterpret_cast<const float4*>(bet)[t];
  float4 y;
  y.x = (v.x - mu) * rstd * gg.x + bb.x;
  y.y = (v.y - mu) * rstd * gg.y + bb.y;
  y.z = (v.z - mu) * rstd * gg.z + bb.z;
  y.w = (v.w - mu) * rstd * gg.w + bb.w;
  reinterpret_cast<float4*>(outf)[(size_t)row * 256 + t] = y;
  if (WRITE_B) {
    uint16_t o[4] = {f2b(y.x), f2b(y.y), f2b(y.z), f2b(y.w)};
    reinterpret_cast<uint2*>(outb)[(size_t)row * 256 + t] = *reinterpret_cast<uint2*>(o);
  }
}

extern "C" void kernel_launch(void* const* d_in, const int* in_sizes, int n_in, void* d_out,
                              int out_size, void* d_ws, size_t ws_size, hipStream_t stream) {
  const float* x = (const float*)d_in[0];
  const float* Wq = (const float*)d_in[1];
  const float* bq = (const float*)d_in[2];
  const float* Wk = (const float*)d_in[3];
  const float* bk = (const float*)d_in[4];
  const float* Wv = (const float*)d_in[5];
  const float* bv = (const float*)d_in[6];
  const float* Wo = (const float*)d_in[7];
  const float* bo = (const float*)d_in[8];
  const float* g1 = (const float*)d_in[9];
  const float* be1 = (const float*)d_in[10];
  const float* W1 = (const float*)d_in[11];
  const float* b1 = (const float*)d_in[12];
  const float* W2 = (const float*)d_in[13];
  const float* b2 = (const float*)d_in[14];
  const float* g2 = (const float*)d_in[15];
  const float* be2 = (const float*)d_in[16];

  char* ws = (char*)d_ws;
  size_t off = 0;
  auto alloc = [&](size_t bytes) {
    char* p = ws + off;
    off += (bytes + 255) & ~(size_t)255;
    return p;
  };
  uint16_t* wt_qkv = (uint16_t*)alloc(3072ull * 1024 * 2);
  uint16_t* wt_o = (uint16_t*)alloc(1024ull * 1024 * 2);
  uint16_t* wt_1 = (uint16_t*)alloc(4096ull * 1024 * 2);
  uint16_t* wt_2 = (uint16_t*)alloc(1024ull * 4096 * 2);
  uint16_t* xb = (uint16_t*)alloc(8192ull * 1024 * 2);  // x bf16; later aliased as ctx
  float* sum1 = (float*)alloc(8192ull * 1024 * 4);      // raw GEMM f32 out (Wo, then FFN2)
  float* x1f = (float*)alloc(8192ull * 1024 * 4);       // LN1 out f32; vt aliases (dead before LN1)
  char* big = alloc(16777216ull + 67108864ull);         // QKV (48MB) -> x1b(16MB)+h(64MB)
  uint16_t* Qbuf = (uint16_t*)big;
  uint16_t* Kbuf = (uint16_t*)(big + 16777216ull);
  uint16_t* Vbuf = (uint16_t*)(big + 2 * 16777216ull);
  uint16_t* vt = (uint16_t*)x1f;
  uint16_t* ctx = xb;
  uint16_t* x1b = (uint16_t*)big;
  uint16_t* hbuf = (uint16_t*)(big + 16777216ull);
  (void)ws_size;

  // 1. weight prep
  k_tcast<<<dim3(32, 32), 256, 0, stream>>>(Wq, wt_qkv, 1024, 1024);
  k_tcast<<<dim3(32, 32), 256, 0, stream>>>(Wk, wt_qkv + 1024 * 1024, 1024, 1024);
  k_tcast<<<dim3(32, 32), 256, 0, stream>>>(Wv, wt_qkv + 2 * 1024 * 1024, 1024, 1024);
  k_tcast<<<dim3(32, 32), 256, 0, stream>>>(Wo, wt_o, 1024, 1024);
  k_tcast<<<dim3(128, 32), 256, 0, stream>>>(W1, wt_1, 1024, 4096);
  k_tcast<<<dim3(32, 128), 256, 0, stream>>>(W2, wt_2, 4096, 1024);
  // 2. cast x
  k_castx<<<8192, 256, 0, stream>>>(x, xb);
  // 3. QKV projection, BN=128 -> 768 blocks = exactly 3 full dispatch waves (no tail idle)
  k_gemm2<128, MODE_QKV><<<768, 512, 0, stream>>>(
      xb, wt_qkv, 8192, 3072, 1024, 24, bq, bk, bv, Qbuf, Kbuf, Vbuf, nullptr);
  // 3.5 V transpose
  k_vtrans<<<dim3(32, 64), 256, 0, stream>>>(Vbuf, vt);
  // 4. attention -> ctx (XCD-local bh grouping)
  k_attn<<<1024, 256, 0, stream>>>(Qbuf, Kbuf, vt, ctx);
  // 5. Wo projection raw -> sum1 (bias+residual folded into LN1)
  k_gemm2<128, MODE_RAW><<<256, 512, 0, stream>>>(
      ctx, wt_o, 8192, 1024, 1024, 8, nullptr, nullptr, nullptr, nullptr, nullptr, nullptr, sum1);
  // 6. LN1(sum1 + bo + x) -> x1 (f32 + bf16)
  k_ln<true><<<8192, 256, 0, stream>>>(sum1, bo, x, g1, be1, x1f, x1b);
  // 7. FFN1: relu(x1 @ W1 + b1) -> h bf16
  k_gemm2<256, MODE_RELU><<<512, 512, 0, stream>>>(
      x1b, wt_1, 8192, 4096, 1024, 16, b1, nullptr, nullptr, hbuf, nullptr, nullptr, nullptr);
  // 8. FFN2 raw -> sum1
  k_gemm2<128, MODE_RAW><<<256, 512, 0, stream>>>(
      hbuf, wt_2, 8192, 1024, 4096, 8, nullptr, nullptr, nullptr, nullptr, nullptr, nullptr, sum1);
  // 9. LN2(sum1 + b2 + x1f) -> output (f32)
  k_ln<false><<<8192, 256, 0, stream>>>(sum1, b2, x1f, g2, be2, (float*)d_out, nullptr);
}